// Round 1
// baseline (50.551 us; speedup 1.0000x reference)
//
#include <hip/hip_runtime.h>

// Problem constants (match reference)
#define PNX 432
#define PNY 496
#define PNC 64
#define PLANE (PNY * PNX)   // 214272, divisible by 256

// ---------------- map-based gather path ----------------

// Init map[] to -1 (one int per output spatial cell), vectorized int4.
__global__ void pp_init_map(int4* __restrict__ map4, int n4) {
    int t = blockIdx.x * blockDim.x + threadIdx.x;
    if (t < n4) {
        map4[t] = make_int4(-1, -1, -1, -1);
    }
}

// Scatter pillar index p into map at its global cell.
__global__ void pp_scatter_map(const int4* __restrict__ coords,
                               int* __restrict__ map, int P) {
    int p = blockIdx.x * blockDim.x + threadIdx.x;
    if (p >= P) return;
    int4 c = coords[p];              // (b, z, y, x)
    int gidx = c.x * PLANE + c.y + c.z * PNX + c.w;
    map[gidx] = p;
}

// One thread per 4 consecutive spatial cells; loops over 64 channels,
// writing one coalesced float4 per iteration. Writes every output element
// (zeros for empty cells) -> no separate zero-fill needed.
__global__ void pp_gather(const float* __restrict__ feat,
                          const int* __restrict__ map,
                          float* __restrict__ out, int ncells4) {
    int t = blockIdx.x * blockDim.x + threadIdx.x;
    if (t >= ncells4) return;
    int cell0 = t * 4;
    int b = cell0 / PLANE;
    int spat = cell0 - b * PLANE;

    int4 pm = *reinterpret_cast<const int4*>(map + cell0);
    const float* f0 = feat + (long)pm.x * PNC;
    const float* f1 = feat + (long)pm.y * PNC;
    const float* f2 = feat + (long)pm.z * PNC;
    const float* f3 = feat + (long)pm.w * PNC;

    float4* outbase =
        reinterpret_cast<float4*>(out + (size_t)b * PNC * PLANE + spat);

    #pragma unroll 8
    for (int c = 0; c < PNC; ++c) {
        float4 v;
        v.x = (pm.x >= 0) ? f0[c] : 0.0f;
        v.y = (pm.y >= 0) ? f1[c] : 0.0f;
        v.z = (pm.z >= 0) ? f2[c] : 0.0f;
        v.w = (pm.w >= 0) ? f3[c] : 0.0f;
        outbase[(size_t)c * (PLANE / 4)] = v;
    }
}

// ---------------- fallback path (ws too small) ----------------

__global__ void pp_zero_out(float4* __restrict__ out4, size_t n4) {
    size_t t = (size_t)blockIdx.x * blockDim.x + threadIdx.x;
    size_t stride = (size_t)gridDim.x * blockDim.x;
    float4 z = make_float4(0.f, 0.f, 0.f, 0.f);
    for (size_t i = t; i < n4; i += stride) out4[i] = z;
}

__global__ void pp_scatter_direct(const float* __restrict__ feat,
                                  const int4* __restrict__ coords,
                                  float* __restrict__ out, int P) {
    int t = blockIdx.x * blockDim.x + threadIdx.x;
    int p = t >> 6;
    int c = t & 63;
    if (p >= P) return;
    int4 co = coords[p];
    size_t oidx = ((size_t)(co.x * PNC + c)) * PLANE + co.y + co.z * PNX + co.w;
    out[oidx] = feat[p * PNC + c];
}

extern "C" void kernel_launch(void* const* d_in, const int* in_sizes, int n_in,
                              void* d_out, int out_size, void* d_ws, size_t ws_size,
                              hipStream_t stream) {
    const float* feat = (const float*)d_in[0];
    const int4* coords = (const int4*)d_in[1];
    float* out = (float*)d_out;

    const int P = in_sizes[0] / PNC;                 // 64000
    const int B = out_size / (PNC * PLANE);          // 4
    const int ncells = B * PLANE;                    // 857088
    const size_t mapBytes = (size_t)ncells * sizeof(int);

    if (ws_size >= mapBytes) {
        int* map = (int*)d_ws;
        int n4 = ncells / 4;                         // 214272
        // 1. map = -1
        pp_init_map<<<(n4 + 255) / 256, 256, 0, stream>>>((int4*)map, n4);
        // 2. scatter pillar ids into map
        pp_scatter_map<<<(P + 255) / 256, 256, 0, stream>>>(coords, map, P);
        // 3. gather: write every output element (coalesced float4)
        pp_gather<<<(n4 + 255) / 256, 256, 0, stream>>>(feat, map, out, n4);
    } else {
        // Fallback: zero-fill + direct scatter (correct but more HBM traffic)
        size_t n4 = (size_t)out_size / 4;
        pp_zero_out<<<2048, 256, 0, stream>>>((float4*)out, n4);
        int total = P * PNC;
        pp_scatter_direct<<<(total + 255) / 256, 256, 0, stream>>>(feat, coords, out, P);
    }
}